// Round 15
// baseline (133.309 us; speedup 1.0000x reference)
//
#include <hip/hip_runtime.h>
#include <hip/hip_fp16.h>
#include <math.h>

#define HW 256
#define BCN 12                  // B*C
#define NF 32                   // filters used (last of 33 dropped)
#define R_TOTAL 25165824        // BCN*HW*HW*NF

// ---------------- fp16 pack helpers ----------------
__device__ __forceinline__ float2 h2f(unsigned u){
  return __half22float2(__builtin_bit_cast(__half2, u));
}
__device__ __forceinline__ unsigned f2h(float2 v){
  return __builtin_bit_cast(unsigned, __floats2half2_rn(v.x, v.y));
}

// ---------------- dual-complex (2-way ILP) helpers ----------------
__device__ __forceinline__ float4 c4add(float4 a,float4 b){
  return make_float4(a.x+b.x,a.y+b.y,a.z+b.z,a.w+b.w);}
__device__ __forceinline__ float4 c4sub(float4 a,float4 b){
  return make_float4(a.x-b.x,a.y-b.y,a.z-b.z,a.w-b.w);}
__device__ __forceinline__ float4 c4mul(float2 w, float4 v){
  return make_float4(w.x*v.x - w.y*v.y, w.x*v.y + w.y*v.x,
                     w.x*v.z - w.y*v.w, w.x*v.w + w.y*v.z);}
__device__ __forceinline__ float4 fma4s(float s, float4 t, float4 o){
  return make_float4(fmaf(s,t.x,o.x), fmaf(s,t.y,o.y),
                     fmaf(s,t.z,o.z), fmaf(s,t.w,o.w));}
template<int SGN>
__device__ __forceinline__ float4 rots(float4 v){   // * SGN*i
  return (SGN>0) ? make_float4(-v.y,v.x,-v.w,v.z)
                 : make_float4(v.y,-v.x,v.w,-v.z);}
__device__ __forceinline__ float4 shfl_xor4(float4 v,int m){
  return make_float4(__shfl_xor(v.x,m,64),__shfl_xor(v.y,m,64),
                     __shfl_xor(v.z,m,64),__shfl_xor(v.w,m,64));}

// ---- DPP lane exchange (VALU pipe): xor1=quad_perm(1,0,3,2)=0xB1,
// xor2=quad_perm(2,3,0,1)=0x4E, xor8=row_ror:8=0x128 ----
// NOTE: permlane16/32_swap tried r6/r7/r9 under three semantic models; all
// failed identically. Banned.
template<int CTRL>
__device__ __forceinline__ float dpp_f(float x){
  return __builtin_bit_cast(float,
    __builtin_amdgcn_update_dpp(0, __builtin_bit_cast(int, x), CTRL, 0xF, 0xF, true));
}
template<int CTRL>
__device__ __forceinline__ float4 dpp4(float4 v){
  return make_float4(dpp_f<CTRL>(v.x), dpp_f<CTRL>(v.y),
                     dpp_f<CTRL>(v.z), dpp_f<CTRL>(v.w));
}
__device__ __forceinline__ float xor4_f(float x){      // x[lane^4], VALU-only
  return dpp_f<0x141>(dpp_f<0x1B>(x));
}

// ---- per-lane twiddles: V_m = (lane&m)? W_{2m}^{lane&(m-1)} : 1 ----
struct Tw {
  float2 V2,V4,V8,V16,V32,t64,t128;
  float s1,s2,s4,s8,s16,s32;
};
template<int SGN>
__device__ __forceinline__ void make_tw(Tw &T, int lane){
  const float g = (SGN>0)? 1.0f : -1.0f;
  float s,c;
  sincospif((float)(lane&1)*0.5f,&s,&c);
  T.V2  = (lane&2)?  make_float2(c,g*s) : make_float2(1.f,0.f);
  sincospif((float)(lane&3)*0.25f,&s,&c);
  T.V4  = (lane&4)?  make_float2(c,g*s) : make_float2(1.f,0.f);
  sincospif((float)(lane&7)*0.125f,&s,&c);
  T.V8  = (lane&8)?  make_float2(c,g*s) : make_float2(1.f,0.f);
  sincospif((float)(lane&15)*0.0625f,&s,&c);
  T.V16 = (lane&16)? make_float2(c,g*s) : make_float2(1.f,0.f);
  sincospif((float)(lane&31)*0.03125f,&s,&c);
  T.V32 = (lane&32)? make_float2(c,g*s) : make_float2(1.f,0.f);
  sincospif((float)lane*(1.0f/64.0f),&s,&c);  T.t64 = make_float2(c,g*s);
  sincospif((float)lane*(1.0f/128.0f),&s,&c); T.t128= make_float2(c,g*s);
  T.s1=(lane&1)?-1.f:1.f;  T.s2=(lane&2)?-1.f:1.f;  T.s4=(lane&4)?-1.f:1.f;
  T.s8=(lane&8)?-1.f:1.f;  T.s16=(lane&16)?-1.f:1.f; T.s32=(lane&32)?-1.f:1.f;
}

// ---- unified 256-pt FFT x2 (DIT, select-free). Input: chunk c[0..3] at
// float index 4*brev6(lane): e0=c0, e1=c2, e2=c1, e3=c3. Output: e[r] holds
// X[64r+lane] (natural order). SGN=-1 forward DFT, SGN=+1 inverse (unnorm).
// Proven config (round 5, 130 us pass): DPP for masks 1/2/8, shfl for 4/16/32.
template<int SGN>
__device__ __forceinline__ void fft4(float4 e[4], const Tw &T, int lane){
  // mask1 (DPP, V=1)
#pragma unroll
  for(int r=0;r<4;++r){
    float4 o = dpp4<0xB1>(e[r]);
    e[r] = fma4s(T.s1, e[r], o);
  }
  // mask2 (DPP)
#pragma unroll
  for(int r=0;r<4;++r){
    float4 t = c4mul(T.V2, e[r]);
    float4 o = dpp4<0x4E>(t);
    e[r] = fma4s(T.s2, t, o);
  }
  // mask4 (DS shfl)
#pragma unroll
  for(int r=0;r<4;++r){
    float4 t = c4mul(T.V4, e[r]);
    float4 o = shfl_xor4(t,4);
    e[r] = fma4s(T.s4, t, o);
  }
  // mask8 (DPP row_ror:8)
#pragma unroll
  for(int r=0;r<4;++r){
    float4 t = c4mul(T.V8, e[r]);
    float4 o = dpp4<0x128>(t);
    e[r] = fma4s(T.s8, t, o);
  }
  // mask16 (DS shfl)
#pragma unroll
  for(int r=0;r<4;++r){
    float4 t = c4mul(T.V16, e[r]);
    float4 o = shfl_xor4(t,16);
    e[r] = fma4s(T.s16, t, o);
  }
  // mask32 (DS shfl)
#pragma unroll
  for(int r=0;r<4;++r){
    float4 t = c4mul(T.V32, e[r]);
    float4 o = shfl_xor4(t,32);
    e[r] = fma4s(T.s32, t, o);
  }
  // len128: pairs (0,1),(2,3), twiddle W_128^lane
  float4 t = c4mul(T.t64, e[1]); e[1]=c4sub(e[0],t); e[0]=c4add(e[0],t);
  t = c4mul(T.t64, e[3]); e[3]=c4sub(e[2],t); e[2]=c4add(e[2],t);
  // len256: pairs (0,2),(1,3); pair (1,3) twiddle W_256^{lane+64} = t128*SGN*i
  t = c4mul(T.t128, e[2]); e[2]=c4sub(e[0],t); e[0]=c4add(e[0],t);
  t = c4mul(T.t128, e[3]); t = rots<SGN>(t);
  e[3]=c4sub(e[1],t); e[1]=c4add(e[1],t);
}

// ---------- prep: psiP[j][v][u] = (f[u,v]+f[-u,-v])*0.5/rms[j], fp16, transposed
__global__ __launch_bounds__(256) void k_prep(const float* __restrict__ filt,
                                              const float* __restrict__ rms,
                                              __half* __restrict__ psiP){
  __shared__ float tile[32][257];
  int j = blockIdx.y, u0 = blockIdx.x<<5, tid = threadIdx.x;
  float rinv = 1.0f / rms[j];
  const float* fj = filt + (size_t)j*HW*HW;
#pragma unroll 4
  for(int k=0;k<32;++k){
    int u = u0+k, v = tid;
    int u2 = (HW-u)&255, v2 = (HW-v)&255;
    tile[k][v] = (fj[(size_t)u*HW+v] + fj[(size_t)u2*HW+v2])*0.5f*rinv;
  }
  __syncthreads();
  __half* pj = psiP + (size_t)j*HW*HW + u0;
#pragma unroll 4
  for(int it=0; it<32; ++it){
    int v = (it<<3) + (tid>>5), ul = tid&31;
    pj[(size_t)v*HW + ul] = __float2half(tile[ul][v]);
  }
}

// ---------- fwd rows: xc=(tg-pr)+i*ir, DIT FFT over w -> X1[bc][h][v] natural
__global__ __launch_bounds__(256) void k_fwd_rows(const float* __restrict__ tg,
                                                  const float* __restrict__ pr,
                                                  const float* __restrict__ ir,
                                                  float2* __restrict__ X1){
  int tid=threadIdx.x, lane=tid&63, wv=tid>>6;
  Tw T; make_tw<-1>(T,lane);
  int bc = blockIdx.x>>5;
  int h0 = ((blockIdx.x&31)<<3) | (wv<<1);
  size_t b0 = ((size_t)bc*HW+h0)*HW;
  size_t b1 = b0 + HW;
  int cb4 = (int)((__brev((unsigned)lane)>>26)<<2);
  float4 t0 = *(const float4*)(tg+b0+cb4);
  float4 p0 = *(const float4*)(pr+b0+cb4);
  float4 i0 = *(const float4*)(ir+b0+cb4);
  float4 t1 = *(const float4*)(tg+b1+cb4);
  float4 p1 = *(const float4*)(pr+b1+cb4);
  float4 i1 = *(const float4*)(ir+b1+cb4);
  float4 e[4];
  e[0]=make_float4(t0.x-p0.x, i0.x, t1.x-p1.x, i1.x);
  e[2]=make_float4(t0.y-p0.y, i0.y, t1.y-p1.y, i1.y);
  e[1]=make_float4(t0.z-p0.z, i0.z, t1.z-p1.z, i1.z);
  e[3]=make_float4(t0.w-p0.w, i0.w, t1.w-p1.w, i1.w);
  fft4<-1>(e,T,lane);
#pragma unroll
  for(int r=0;r<4;++r){
    X1[b0 + (r<<6)+lane] = make_float2(e[r].x,e[r].y);
    X1[b1 + (r<<6)+lane] = make_float2(e[r].z,e[r].w);
  }
}

// ---------- fwd cols: DIT FFT over h, scale 1/65536 -> T2h[bc][v][u] fp16 natural
__global__ __launch_bounds__(256) void k_fwd_cols(const float2* __restrict__ X1,
                                                  unsigned* __restrict__ T2h){
  int tid=threadIdx.x, lane=tid&63, wv=tid>>6;
  Tw T; make_tw<-1>(T,lane);
  int bc = blockIdx.x>>5;
  int v0 = ((blockIdx.x&31)<<3) | (wv<<1);   // column pair (v0, v0+1)
  int b4 = (int)((__brev((unsigned)lane)>>26)<<2);
  const float2* xb = X1 + (size_t)bc*HW*HW + v0;
  float4 L0 = *(const float4*)(xb + (size_t)(b4+0)*HW);
  float4 L1 = *(const float4*)(xb + (size_t)(b4+1)*HW);
  float4 L2 = *(const float4*)(xb + (size_t)(b4+2)*HW);
  float4 L3 = *(const float4*)(xb + (size_t)(b4+3)*HW);
  float4 e[4];
  e[0]=L0; e[2]=L1; e[1]=L2; e[3]=L3;
  fft4<-1>(e,T,lane);
  const float s = 1.0f/65536.0f;
  unsigned* t0 = T2h + (size_t)bc*HW*HW + (size_t)v0*HW;
#pragma unroll
  for(int r=0;r<4;++r){
    int u = (r<<6)+lane;
    t0[u]    = f2h(make_float2(e[r].x*s, e[r].y*s));
    t0[HW+u] = f2h(make_float2(e[r].z*s, e[r].w*s));
  }
}

// ---------- B1: Y = T2h*psiP, inverse FFT over u -> Zh[bcl][h][j][v] fp16
// grid = (NF, 16, bcc): j varies fastest -> T2h slice reused from L2.
// Zh layout is h-major so each b2 block reads one contiguous 32 KB region.
__global__ __launch_bounds__(256) void k_b1(const unsigned* __restrict__ T2h,
                                            const __half* __restrict__ psiP,
                                            unsigned* __restrict__ Zh,
                                            int bc0){
  int tid=threadIdx.x, lane=tid&63, wv=tid>>6;
  Tw T; make_tw<1>(T,lane);
  int j  = blockIdx.x;
  int vt = blockIdx.y<<4;
  int bcl= blockIdx.z;
  int bc = bc0 + bcl;
  int cb = __brev((unsigned)lane)>>26;
  int u0 = cb<<2;
  int vb = vt + (wv<<2);
  const unsigned* tb  = T2h  + (size_t)bc*HW*HW + u0;
  const __half*   pjb = psiP + (size_t)j*HW*HW + u0;
  float4 ea[4], eb[4];
#pragma unroll
  for(int p=0;p<2;++p){
    int v0 = vb + (p<<1);
    uint4 tA = *(const uint4*)(tb + (size_t)v0*HW);
    uint4 tB = *(const uint4*)(tb + (size_t)(v0+1)*HW);
    uint2 puA = *(const uint2*)(pjb + (size_t)v0*HW);
    uint2 puB = *(const uint2*)(pjb + (size_t)(v0+1)*HW);
    float2 pA01 = h2f(puA.x), pA23 = h2f(puA.y);
    float2 pB01 = h2f(puB.x), pB23 = h2f(puB.y);
    float2 a0=h2f(tA.x), a1=h2f(tA.y), a2=h2f(tA.z), a3=h2f(tA.w);
    float2 c0=h2f(tB.x), c1=h2f(tB.y), c2=h2f(tB.z), c3=h2f(tB.w);
    float4* e = p? eb : ea;
    e[0]=make_float4(a0.x*pA01.x, a0.y*pA01.x, c0.x*pB01.x, c0.y*pB01.x);
    e[2]=make_float4(a1.x*pA01.y, a1.y*pA01.y, c1.x*pB01.y, c1.y*pB01.y);
    e[1]=make_float4(a2.x*pA23.x, a2.y*pA23.x, c2.x*pB23.x, c2.y*pB23.x);
    e[3]=make_float4(a3.x*pA23.y, a3.y*pA23.y, c3.x*pB23.y, c3.y*pB23.y);
    fft4<1>(e,T,lane);
  }
  // store to Zh[bcl][h][j][v]: stride per h = NF*HW
  unsigned* zb = Zh + ((size_t)bcl*HW*NF + j)*HW + vb;
#pragma unroll
  for(int r=0;r<4;++r){
    int h = (r<<6)+lane;
    *(uint4*)(zb + (size_t)h*NF*HW) =
      make_uint4(f2h(make_float2(ea[r].x,ea[r].y)),
                 f2h(make_float2(ea[r].z,ea[r].w)),
                 f2h(make_float2(eb[r].x,eb[r].y)),
                 f2h(make_float2(eb[r].z,eb[r].w)));
  }
}

// ---------- B2: inverse FFT over v, pointwise R, DIRECT register store ----
// Wave wv owns j in [8wv, 8wv+8) for its h. After fft4, thread (lane) holds
// R for (w=64r+lane) x its wave's 8 j's == exactly the out[w*32+j] footprint
// of 4x 32B contiguous stores. NO LDS, NO barriers, fp32 out path.
__global__ __launch_bounds__(256) void k_b2(const unsigned* __restrict__ Zh,
                                            float* __restrict__ out,
                                            double* __restrict__ part,
                                            int bc0){
  int tid=threadIdx.x, lane=tid&63, wv=tid>>6;
  int h = blockIdx.x;
  int bcl = blockIdx.y;
  int bc = bc0 + bcl;
  int cb = __brev((unsigned)lane)>>26;
  const unsigned* zb = Zh + ((size_t)bcl*HW + h)*NF*HW + (cb<<2);
  // ---- hoisted loads: 8 x uint4, all issued before any cross-lane op ----
  uint4 L[8];
#pragma unroll
  for(int c=0;c<4;++c){
    int j0 = (wv<<3) + (c<<1);
    L[2*c]   = *(const uint4*)(zb + (size_t)j0*HW);
    L[2*c+1] = *(const uint4*)(zb + (size_t)(j0+1)*HW);
  }
  Tw T; make_tw<1>(T,lane);
  float lsum=0.0f, lsq=0.0f;
  float R[4][8];                       // [c][r*2 + {0,1}]: j = 8wv+2c+{0,1}
#pragma unroll
  for(int c=0;c<4;++c){
    uint4 z0 = L[2*c];
    uint4 z1 = L[2*c+1];
    float2 a0=h2f(z0.x),a1=h2f(z0.y),a2=h2f(z0.z),a3=h2f(z0.w);
    float2 c0=h2f(z1.x),c1=h2f(z1.y),c2=h2f(z1.z),c3=h2f(z1.w);
    float4 e[4];
    e[0]=make_float4(a0.x,a0.y,c0.x,c0.y);
    e[2]=make_float4(a1.x,a1.y,c1.x,c1.y);
    e[1]=make_float4(a2.x,a2.y,c2.x,c2.y);
    e[3]=make_float4(a3.x,a3.y,c3.x,c3.y);
    fft4<1>(e,T,lane);
#pragma unroll
    for(int r=0;r<4;++r){
      float t1 = fmaxf(fabsf(e[r].x)-e[r].y, 0.0f);
      float R0 = 1.0f - fmaxf(1.0f-t1, 0.0f);
      float t2 = fmaxf(fabsf(e[r].z)-e[r].w, 0.0f);
      float R1 = 1.0f - fmaxf(1.0f-t2, 0.0f);
      R[c][r*2]   = R0;
      R[c][r*2+1] = R1;
      lsum += R0; lsum += R1;
      lsq = fmaf(R0,R0,lsq); lsq = fmaf(R1,R1,lsq);
    }
  }
  // direct transposed store: w = 64r+lane, 8 consecutive j's (2 float4)
  float* ob = out + (size_t)bc*(HW*HW*NF) + (size_t)h*(HW*NF) + (wv<<3);
#pragma unroll
  for(int r=0;r<4;++r){
    int w = (r<<6)+lane;
    float4* dst = (float4*)(ob + (size_t)w*NF);
    dst[0] = make_float4(R[0][2*r],R[0][2*r+1],R[1][2*r],R[1][2*r+1]);
    dst[1] = make_float4(R[2][2*r],R[2][2*r+1],R[3][2*r],R[3][2*r+1]);
  }
  // wave reduce: masks 32/16 on shfl, 8/4/2/1 on DPP (VALU)
  lsum += __shfl_xor(lsum,32,64);          lsq += __shfl_xor(lsq,32,64);
  lsum += __shfl_xor(lsum,16,64);          lsq += __shfl_xor(lsq,16,64);
  lsum += dpp_f<0x128>(lsum);              lsq += dpp_f<0x128>(lsq);
  lsum += xor4_f(lsum);                    lsq += xor4_f(lsq);
  lsum += dpp_f<0x4E>(lsum);               lsq += dpp_f<0x4E>(lsq);
  lsum += dpp_f<0xB1>(lsum);               lsq += dpp_f<0xB1>(lsq);
  if(lane==0){
    size_t slot = (((size_t)bc*HW + h)*4 + wv)*2;
    part[slot+0] = (double)lsum;
    part[slot+1] = (double)lsq;
  }
}

// ---------- finalize: deterministic mean/std (ddof=1) per batch ----------
__global__ __launch_bounds__(256) void k_fin(const double* __restrict__ part,
                                             float* __restrict__ out){
  __shared__ double red[256];
  int b = blockIdx.x, t = threadIdx.x;
  double s=0.0, q=0.0;
  for(int i=t;i<3072;i+=256){   // 3 bc * 256 h * 4 wv slots per batch
    size_t s0 = ((size_t)b*3072+i)*2;
    s += part[s0+0];
    q += part[s0+1];
  }
  red[t]=s; __syncthreads();
  for(int k=128;k>0;k>>=1){ if(t<k) red[t]+=red[t+k]; __syncthreads(); }
  double S=red[0]; __syncthreads();
  red[t]=q; __syncthreads();
  for(int k=128;k>0;k>>=1){ if(t<k) red[t]+=red[t+k]; __syncthreads(); }
  if(t==0){
    const double N = 6291456.0;          // C*H*W*NF
    double m = S/N;
    double var = (red[0] - S*S/N)/(N-1.0);
    out[R_TOTAL+b] = (float)m;
    out[R_TOTAL+4+b] = (float)(var>0.0? sqrt(var):0.0);
  }
}

extern "C" void kernel_launch(void* const* d_in, const int* in_sizes, int n_in,
                              void* d_out, int out_size, void* d_ws, size_t ws_size,
                              hipStream_t stream){
  (void)in_sizes; (void)n_in; (void)out_size;
  const float* tg   = (const float*)d_in[0];
  const float* pr   = (const float*)d_in[1];
  const float* ir   = (const float*)d_in[2];
  const float* filt = (const float*)d_in[3];
  const float* rms  = (const float*)d_in[4];
  float* out = (float*)d_out;

  char* ws = (char*)d_ws;
  double* part = (double*)(ws + 128);
  size_t off = 128 + (size_t)BCN*HW*4*2*sizeof(double);            // part: 197 KB
  __half* psiP = (__half*)(ws + off);  off += (size_t)NF*HW*HW*2;  // 4.19 MB
  float2* X1   = (float2*)(ws + off);  off += (size_t)BCN*HW*HW*8; // 6.29 MB
  unsigned* T2h= (unsigned*)(ws + off);off += (size_t)BCN*HW*HW*4; // 3.15 MB
  unsigned* Zh = (unsigned*)(ws + off);
  const size_t fixedB = off;
  const size_t zPerBc = (size_t)NF*HW*HW*4;                        // 8.39 MB

  // bcc=12: single chunk (r8/r13: chunk-splitting regresses).
  int bcc = 1;
  const int cand[6] = {12,6,4,3,2,1};
  for(int i=0;i<6;++i){
    if(fixedB + (size_t)cand[i]*zPerBc <= ws_size){ bcc = cand[i]; break; }
  }

  k_prep<<<dim3(8,NF), 256, 0, stream>>>(filt, rms, psiP);
  k_fwd_rows<<<dim3(BCN*32), 256, 0, stream>>>(tg, pr, ir, X1);
  k_fwd_cols<<<dim3(BCN*32), 256, 0, stream>>>(X1, T2h);

  int nch = BCN/bcc;
  for(int c=0;c<nch;++c){
    int bc0 = c*bcc;
    k_b1<<<dim3(NF,16,bcc), 256, 0, stream>>>(T2h, psiP, Zh, bc0);
    k_b2<<<dim3(HW,bcc), 256, 0, stream>>>(Zh, out, part, bc0);
  }
  k_fin<<<4, 256, 0, stream>>>(part, out);
}

// Round 16
// 124.990 us; speedup vs baseline: 1.0666x; 1.0666x over previous
//
#include <hip/hip_runtime.h>
#include <hip/hip_fp16.h>
#include <math.h>

#define HW 256
#define BCN 12                  // B*C
#define NF 32                   // filters used (last of 33 dropped)
#define R_TOTAL 25165824        // BCN*HW*HW*NF

// ---------------- fp16 pack helpers ----------------
__device__ __forceinline__ float2 h2f(unsigned u){
  return __half22float2(__builtin_bit_cast(__half2, u));
}
__device__ __forceinline__ unsigned f2h(float2 v){
  return __builtin_bit_cast(unsigned, __floats2half2_rn(v.x, v.y));
}

// ---------------- dual-complex (2-way ILP) helpers ----------------
__device__ __forceinline__ float4 c4add(float4 a,float4 b){
  return make_float4(a.x+b.x,a.y+b.y,a.z+b.z,a.w+b.w);}
__device__ __forceinline__ float4 c4sub(float4 a,float4 b){
  return make_float4(a.x-b.x,a.y-b.y,a.z-b.z,a.w-b.w);}
__device__ __forceinline__ float4 c4mul(float2 w, float4 v){
  return make_float4(w.x*v.x - w.y*v.y, w.x*v.y + w.y*v.x,
                     w.x*v.z - w.y*v.w, w.x*v.w + w.y*v.z);}
__device__ __forceinline__ float4 fma4s(float s, float4 t, float4 o){
  return make_float4(fmaf(s,t.x,o.x), fmaf(s,t.y,o.y),
                     fmaf(s,t.z,o.z), fmaf(s,t.w,o.w));}
template<int SGN>
__device__ __forceinline__ float4 rots(float4 v){   // * SGN*i
  return (SGN>0) ? make_float4(-v.y,v.x,-v.w,v.z)
                 : make_float4(v.y,-v.x,v.w,-v.z);}
__device__ __forceinline__ float4 shfl_xor4(float4 v,int m){
  return make_float4(__shfl_xor(v.x,m,64),__shfl_xor(v.y,m,64),
                     __shfl_xor(v.z,m,64),__shfl_xor(v.w,m,64));}

// ---- DPP lane exchange (VALU pipe): xor1=quad_perm(1,0,3,2)=0xB1,
// xor2=quad_perm(2,3,0,1)=0x4E, xor8=row_ror:8=0x128 ----
// NOTE: permlane16/32_swap tried r6/r7/r9 under three semantic models; all
// failed identically. Banned.
template<int CTRL>
__device__ __forceinline__ float dpp_f(float x){
  return __builtin_bit_cast(float,
    __builtin_amdgcn_update_dpp(0, __builtin_bit_cast(int, x), CTRL, 0xF, 0xF, true));
}
template<int CTRL>
__device__ __forceinline__ float4 dpp4(float4 v){
  return make_float4(dpp_f<CTRL>(v.x), dpp_f<CTRL>(v.y),
                     dpp_f<CTRL>(v.z), dpp_f<CTRL>(v.w));
}
__device__ __forceinline__ float xor4_f(float x){      // x[lane^4], VALU-only
  return dpp_f<0x141>(dpp_f<0x1B>(x));
}

// ---- per-lane twiddles: V_m = (lane&m)? W_{2m}^{lane&(m-1)} : 1 ----
struct Tw {
  float2 V2,V4,V8,V16,V32,t64,t128;
  float s1,s2,s4,s8,s16,s32;
};
template<int SGN>
__device__ __forceinline__ void make_tw(Tw &T, int lane){
  const float g = (SGN>0)? 1.0f : -1.0f;
  float s,c;
  sincospif((float)(lane&1)*0.5f,&s,&c);
  T.V2  = (lane&2)?  make_float2(c,g*s) : make_float2(1.f,0.f);
  sincospif((float)(lane&3)*0.25f,&s,&c);
  T.V4  = (lane&4)?  make_float2(c,g*s) : make_float2(1.f,0.f);
  sincospif((float)(lane&7)*0.125f,&s,&c);
  T.V8  = (lane&8)?  make_float2(c,g*s) : make_float2(1.f,0.f);
  sincospif((float)(lane&15)*0.0625f,&s,&c);
  T.V16 = (lane&16)? make_float2(c,g*s) : make_float2(1.f,0.f);
  sincospif((float)(lane&31)*0.03125f,&s,&c);
  T.V32 = (lane&32)? make_float2(c,g*s) : make_float2(1.f,0.f);
  sincospif((float)lane*(1.0f/64.0f),&s,&c);  T.t64 = make_float2(c,g*s);
  sincospif((float)lane*(1.0f/128.0f),&s,&c); T.t128= make_float2(c,g*s);
  T.s1=(lane&1)?-1.f:1.f;  T.s2=(lane&2)?-1.f:1.f;  T.s4=(lane&4)?-1.f:1.f;
  T.s8=(lane&8)?-1.f:1.f;  T.s16=(lane&16)?-1.f:1.f; T.s32=(lane&32)?-1.f:1.f;
}

// ---- unified 256-pt FFT x2 (DIT, select-free). Input: chunk c[0..3] at
// float index 4*brev6(lane): e0=c0, e1=c2, e2=c1, e3=c3. Output: e[r] holds
// X[64r+lane] (natural order). SGN=-1 forward DFT, SGN=+1 inverse (unnorm).
// Proven config (round 5, 130 us pass): DPP for masks 1/2/8, shfl for 4/16/32.
template<int SGN>
__device__ __forceinline__ void fft4(float4 e[4], const Tw &T, int lane){
  // mask1 (DPP, V=1)
#pragma unroll
  for(int r=0;r<4;++r){
    float4 o = dpp4<0xB1>(e[r]);
    e[r] = fma4s(T.s1, e[r], o);
  }
  // mask2 (DPP)
#pragma unroll
  for(int r=0;r<4;++r){
    float4 t = c4mul(T.V2, e[r]);
    float4 o = dpp4<0x4E>(t);
    e[r] = fma4s(T.s2, t, o);
  }
  // mask4 (DS shfl)
#pragma unroll
  for(int r=0;r<4;++r){
    float4 t = c4mul(T.V4, e[r]);
    float4 o = shfl_xor4(t,4);
    e[r] = fma4s(T.s4, t, o);
  }
  // mask8 (DPP row_ror:8)
#pragma unroll
  for(int r=0;r<4;++r){
    float4 t = c4mul(T.V8, e[r]);
    float4 o = dpp4<0x128>(t);
    e[r] = fma4s(T.s8, t, o);
  }
  // mask16 (DS shfl)
#pragma unroll
  for(int r=0;r<4;++r){
    float4 t = c4mul(T.V16, e[r]);
    float4 o = shfl_xor4(t,16);
    e[r] = fma4s(T.s16, t, o);
  }
  // mask32 (DS shfl)
#pragma unroll
  for(int r=0;r<4;++r){
    float4 t = c4mul(T.V32, e[r]);
    float4 o = shfl_xor4(t,32);
    e[r] = fma4s(T.s32, t, o);
  }
  // len128: pairs (0,1),(2,3), twiddle W_128^lane
  float4 t = c4mul(T.t64, e[1]); e[1]=c4sub(e[0],t); e[0]=c4add(e[0],t);
  t = c4mul(T.t64, e[3]); e[3]=c4sub(e[2],t); e[2]=c4add(e[2],t);
  // len256: pairs (0,2),(1,3); pair (1,3) twiddle W_256^{lane+64} = t128*SGN*i
  t = c4mul(T.t128, e[2]); e[2]=c4sub(e[0],t); e[0]=c4add(e[0],t);
  t = c4mul(T.t128, e[3]); t = rots<SGN>(t);
  e[3]=c4sub(e[1],t); e[1]=c4add(e[1],t);
}

// ---------- prep: psiP[j][v][u] = (f[u,v]+f[-u,-v])*0.5/rms[j], fp16, transposed
__global__ __launch_bounds__(256) void k_prep(const float* __restrict__ filt,
                                              const float* __restrict__ rms,
                                              __half* __restrict__ psiP){
  __shared__ float tile[32][257];
  int j = blockIdx.y, u0 = blockIdx.x<<5, tid = threadIdx.x;
  float rinv = 1.0f / rms[j];
  const float* fj = filt + (size_t)j*HW*HW;
#pragma unroll 4
  for(int k=0;k<32;++k){
    int u = u0+k, v = tid;
    int u2 = (HW-u)&255, v2 = (HW-v)&255;
    tile[k][v] = (fj[(size_t)u*HW+v] + fj[(size_t)u2*HW+v2])*0.5f*rinv;
  }
  __syncthreads();
  __half* pj = psiP + (size_t)j*HW*HW + u0;
#pragma unroll 4
  for(int it=0; it<32; ++it){
    int v = (it<<3) + (tid>>5), ul = tid&31;
    pj[(size_t)v*HW + ul] = __float2half(tile[ul][v]);
  }
}

// ---------- fwd rows: xc=(tg-pr)+i*ir, DIT FFT over w -> X1[bc][h][v] natural
__global__ __launch_bounds__(256) void k_fwd_rows(const float* __restrict__ tg,
                                                  const float* __restrict__ pr,
                                                  const float* __restrict__ ir,
                                                  float2* __restrict__ X1){
  int tid=threadIdx.x, lane=tid&63, wv=tid>>6;
  Tw T; make_tw<-1>(T,lane);
  int bc = blockIdx.x>>5;
  int h0 = ((blockIdx.x&31)<<3) | (wv<<1);
  size_t b0 = ((size_t)bc*HW+h0)*HW;
  size_t b1 = b0 + HW;
  int cb4 = (int)((__brev((unsigned)lane)>>26)<<2);
  float4 t0 = *(const float4*)(tg+b0+cb4);
  float4 p0 = *(const float4*)(pr+b0+cb4);
  float4 i0 = *(const float4*)(ir+b0+cb4);
  float4 t1 = *(const float4*)(tg+b1+cb4);
  float4 p1 = *(const float4*)(pr+b1+cb4);
  float4 i1 = *(const float4*)(ir+b1+cb4);
  float4 e[4];
  e[0]=make_float4(t0.x-p0.x, i0.x, t1.x-p1.x, i1.x);
  e[2]=make_float4(t0.y-p0.y, i0.y, t1.y-p1.y, i1.y);
  e[1]=make_float4(t0.z-p0.z, i0.z, t1.z-p1.z, i1.z);
  e[3]=make_float4(t0.w-p0.w, i0.w, t1.w-p1.w, i1.w);
  fft4<-1>(e,T,lane);
#pragma unroll
  for(int r=0;r<4;++r){
    X1[b0 + (r<<6)+lane] = make_float2(e[r].x,e[r].y);
    X1[b1 + (r<<6)+lane] = make_float2(e[r].z,e[r].w);
  }
}

// ---------- fwd cols: DIT FFT over h, scale 1/65536 -> T2h[bc][v][u] fp16 natural
__global__ __launch_bounds__(256) void k_fwd_cols(const float2* __restrict__ X1,
                                                  unsigned* __restrict__ T2h){
  int tid=threadIdx.x, lane=tid&63, wv=tid>>6;
  Tw T; make_tw<-1>(T,lane);
  int bc = blockIdx.x>>5;
  int v0 = ((blockIdx.x&31)<<3) | (wv<<1);   // column pair (v0, v0+1)
  int b4 = (int)((__brev((unsigned)lane)>>26)<<2);
  const float2* xb = X1 + (size_t)bc*HW*HW + v0;
  float4 L0 = *(const float4*)(xb + (size_t)(b4+0)*HW);
  float4 L1 = *(const float4*)(xb + (size_t)(b4+1)*HW);
  float4 L2 = *(const float4*)(xb + (size_t)(b4+2)*HW);
  float4 L3 = *(const float4*)(xb + (size_t)(b4+3)*HW);
  float4 e[4];
  e[0]=L0; e[2]=L1; e[1]=L2; e[3]=L3;
  fft4<-1>(e,T,lane);
  const float s = 1.0f/65536.0f;
  unsigned* t0 = T2h + (size_t)bc*HW*HW + (size_t)v0*HW;
#pragma unroll
  for(int r=0;r<4;++r){
    int u = (r<<6)+lane;
    t0[u]    = f2h(make_float2(e[r].x*s, e[r].y*s));
    t0[HW+u] = f2h(make_float2(e[r].z*s, e[r].w*s));
  }
}

// ---------- B1: Y = T2h*psiP, inverse FFT over u -> Zh[bcl*NF+j][h][v] fp16
// grid = (NF, 16, bcc): j varies fastest -> T2h slice reused from L2.
__global__ __launch_bounds__(256) void k_b1(const unsigned* __restrict__ T2h,
                                            const __half* __restrict__ psiP,
                                            unsigned* __restrict__ Zh,
                                            int bc0){
  int tid=threadIdx.x, lane=tid&63, wv=tid>>6;
  Tw T; make_tw<1>(T,lane);
  int j  = blockIdx.x;
  int vt = blockIdx.y<<4;
  int bcl= blockIdx.z;
  int bc = bc0 + bcl;
  int cb = __brev((unsigned)lane)>>26;
  int u0 = cb<<2;
  int vb = vt + (wv<<2);
  const unsigned* tb  = T2h  + (size_t)bc*HW*HW + u0;
  const __half*   pjb = psiP + (size_t)j*HW*HW + u0;
  float4 ea[4], eb[4];
#pragma unroll
  for(int p=0;p<2;++p){
    int v0 = vb + (p<<1);
    uint4 tA = *(const uint4*)(tb + (size_t)v0*HW);
    uint4 tB = *(const uint4*)(tb + (size_t)(v0+1)*HW);
    uint2 puA = *(const uint2*)(pjb + (size_t)v0*HW);
    uint2 puB = *(const uint2*)(pjb + (size_t)(v0+1)*HW);
    float2 pA01 = h2f(puA.x), pA23 = h2f(puA.y);
    float2 pB01 = h2f(puB.x), pB23 = h2f(puB.y);
    float2 a0=h2f(tA.x), a1=h2f(tA.y), a2=h2f(tA.z), a3=h2f(tA.w);
    float2 c0=h2f(tB.x), c1=h2f(tB.y), c2=h2f(tB.z), c3=h2f(tB.w);
    float4* e = p? eb : ea;
    e[0]=make_float4(a0.x*pA01.x, a0.y*pA01.x, c0.x*pB01.x, c0.y*pB01.x);
    e[2]=make_float4(a1.x*pA01.y, a1.y*pA01.y, c1.x*pB01.y, c1.y*pB01.y);
    e[1]=make_float4(a2.x*pA23.x, a2.y*pA23.x, c2.x*pB23.x, c2.y*pB23.x);
    e[3]=make_float4(a3.x*pA23.y, a3.y*pA23.y, c3.x*pB23.y, c3.y*pB23.y);
    fft4<1>(e,T,lane);
  }
  unsigned* zb = Zh + (size_t)(bcl*NF + j)*HW*HW + vb;
#pragma unroll
  for(int r=0;r<4;++r){
    int h = (r<<6)+lane;
    *(uint4*)(zb + (size_t)h*HW) =
      make_uint4(f2h(make_float2(ea[r].x,ea[r].y)),
                 f2h(make_float2(ea[r].z,ea[r].w)),
                 f2h(make_float2(eb[r].x,eb[r].y)),
                 f2h(make_float2(eb[r].z,eb[r].w)));
  }
}

// ---------- B2: inverse FFT over v, pointwise R, transpose, partial sums ----
// r12 structure + launch_bounds(256,2): 256-VGPR budget so the allocator can
// keep L[8] + multiple FFT chains live (r12's ILP intent, finally enabled).
__global__ __launch_bounds__(256, 2) void k_b2(const unsigned* __restrict__ Zh,
                                               float* __restrict__ out,
                                               double* __restrict__ part,
                                               int bc0){
  __shared__ float Rt[16*260];
  __shared__ double redS[4], redQ[4];
  int tid=threadIdx.x, lane=tid&63, wv=tid>>6;
  int h = blockIdx.x;
  int bcl = blockIdx.y;
  int bc = bc0 + bcl;
  int cb = __brev((unsigned)lane)>>26;
  const unsigned* zb = Zh + (size_t)bcl*NF*HW*HW + (size_t)h*HW + (cb<<2);
  // ---- hoisted loads: 8 x uint4, issued before any cross-lane op ----
  uint4 L[8];
#pragma unroll
  for(int c=0;c<4;++c){
    int jl0 = (wv<<2) + ((c&1)<<1);
    int j0  = ((c>>1)<<4) + jl0;
    L[2*c]   = *(const uint4*)(zb + (size_t)j0*HW*HW);
    L[2*c+1] = *(const uint4*)(zb + (size_t)(j0+1)*HW*HW);
  }
  Tw T; make_tw<1>(T,lane);
  float lsum=0.0f, lsq=0.0f;
  float* ob = out + (size_t)bc*(HW*HW*NF) + (size_t)h*(HW*NF);
  float R[4][8];                       // [c = jh*2+pp][r*2 + {0,1}]
#pragma unroll
  for(int c=0;c<4;++c){
    uint4 z0 = L[2*c];
    uint4 z1 = L[2*c+1];
    float2 a0=h2f(z0.x),a1=h2f(z0.y),a2=h2f(z0.z),a3=h2f(z0.w);
    float2 c0=h2f(z1.x),c1=h2f(z1.y),c2=h2f(z1.z),c3=h2f(z1.w);
    float4 e[4];
    e[0]=make_float4(a0.x,a0.y,c0.x,c0.y);
    e[2]=make_float4(a1.x,a1.y,c1.x,c1.y);
    e[1]=make_float4(a2.x,a2.y,c2.x,c2.y);
    e[3]=make_float4(a3.x,a3.y,c3.x,c3.y);
    fft4<1>(e,T,lane);
#pragma unroll
    for(int r=0;r<4;++r){
      float t1 = fmaxf(fabsf(e[r].x)-e[r].y, 0.0f);
      float R0 = 1.0f - fmaxf(1.0f-t1, 0.0f);
      float t2 = fmaxf(fabsf(e[r].z)-e[r].w, 0.0f);
      float R1 = 1.0f - fmaxf(1.0f-t2, 0.0f);
      R[c][r*2]   = R0;
      R[c][r*2+1] = R1;
      lsum += R0; lsum += R1;
      lsq = fmaf(R0,R0,lsq); lsq = fmaf(R1,R1,lsq);
    }
  }
  // LDS transpose + coalesced store, two jh halves
#pragma unroll
  for(int jh=0;jh<2;++jh){
    if(jh) __syncthreads();
#pragma unroll
    for(int p=0;p<2;++p){
      int c = jh*2+p;
      int jl0 = (wv<<2)+(p<<1);
#pragma unroll
      for(int r=0;r<4;++r){
        int w = (r<<6)+lane;
        Rt[jl0*260 + w]     = R[c][r*2];
        Rt[(jl0+1)*260 + w] = R[c][r*2+1];
      }
    }
    __syncthreads();
    float vals[16];
#pragma unroll
    for(int k=0;k<16;++k) vals[k]=Rt[k*260+tid];
    float4* dst = (float4*)(ob + (size_t)tid*NF + (jh<<4));
    dst[0]=make_float4(vals[0],vals[1],vals[2],vals[3]);
    dst[1]=make_float4(vals[4],vals[5],vals[6],vals[7]);
    dst[2]=make_float4(vals[8],vals[9],vals[10],vals[11]);
    dst[3]=make_float4(vals[12],vals[13],vals[14],vals[15]);
  }
  // wave reduce: masks 32/16 on shfl, 8/4/2/1 on DPP (VALU)
  lsum += __shfl_xor(lsum,32,64);          lsq += __shfl_xor(lsq,32,64);
  lsum += __shfl_xor(lsum,16,64);          lsq += __shfl_xor(lsq,16,64);
  lsum += dpp_f<0x128>(lsum);              lsq += dpp_f<0x128>(lsq);
  lsum += xor4_f(lsum);                    lsq += xor4_f(lsq);
  lsum += dpp_f<0x4E>(lsum);               lsq += dpp_f<0x4E>(lsq);
  lsum += dpp_f<0xB1>(lsum);               lsq += dpp_f<0xB1>(lsq);
  if(lane==0){ redS[wv]=(double)lsum; redQ[wv]=(double)lsq; }
  __syncthreads();
  if(tid==0){
    double S=redS[0]+redS[1]+redS[2]+redS[3];
    double Q=redQ[0]+redQ[1]+redQ[2]+redQ[3];
    part[((size_t)bc*HW+h)*2+0]=S;
    part[((size_t)bc*HW+h)*2+1]=Q;
  }
}

// ---------- finalize: deterministic mean/std (ddof=1) per batch ----------
__global__ __launch_bounds__(256) void k_fin(const double* __restrict__ part,
                                             float* __restrict__ out){
  __shared__ double red[256];
  int b = blockIdx.x, t = threadIdx.x;
  double s=0.0, q=0.0;
  for(int i=t;i<768;i+=256){
    s += part[((size_t)b*768+i)*2+0];
    q += part[((size_t)b*768+i)*2+1];
  }
  red[t]=s; __syncthreads();
  for(int k=128;k>0;k>>=1){ if(t<k) red[t]+=red[t+k]; __syncthreads(); }
  double S=red[0]; __syncthreads();
  red[t]=q; __syncthreads();
  for(int k=128;k>0;k>>=1){ if(t<k) red[t]+=red[t+k]; __syncthreads(); }
  if(t==0){
    const double N = 6291456.0;          // C*H*W*NF
    double m = S/N;
    double var = (red[0] - S*S/N)/(N-1.0);
    out[R_TOTAL+b] = (float)m;
    out[R_TOTAL+4+b] = (float)(var>0.0? sqrt(var):0.0);
  }
}

extern "C" void kernel_launch(void* const* d_in, const int* in_sizes, int n_in,
                              void* d_out, int out_size, void* d_ws, size_t ws_size,
                              hipStream_t stream){
  (void)in_sizes; (void)n_in; (void)out_size;
  const float* tg   = (const float*)d_in[0];
  const float* pr   = (const float*)d_in[1];
  const float* ir   = (const float*)d_in[2];
  const float* filt = (const float*)d_in[3];
  const float* rms  = (const float*)d_in[4];
  float* out = (float*)d_out;

  char* ws = (char*)d_ws;
  double* part = (double*)(ws + 128);
  size_t off = 128 + (size_t)BCN*HW*2*sizeof(double);              // part: 49 KB
  __half* psiP = (__half*)(ws + off);  off += (size_t)NF*HW*HW*2;  // 4.19 MB
  float2* X1   = (float2*)(ws + off);  off += (size_t)BCN*HW*HW*8; // 6.29 MB
  unsigned* T2h= (unsigned*)(ws + off);off += (size_t)BCN*HW*HW*4; // 3.15 MB
  unsigned* Zh = (unsigned*)(ws + off);
  const size_t fixedB = off;
  const size_t zPerBc = (size_t)NF*HW*HW*4;                        // 8.39 MB

  // bcc=12: single chunk (r8/r13: chunk-splitting regresses).
  int bcc = 1;
  const int cand[6] = {12,6,4,3,2,1};
  for(int i=0;i<6;++i){
    if(fixedB + (size_t)cand[i]*zPerBc <= ws_size){ bcc = cand[i]; break; }
  }

  k_prep<<<dim3(8,NF), 256, 0, stream>>>(filt, rms, psiP);
  k_fwd_rows<<<dim3(BCN*32), 256, 0, stream>>>(tg, pr, ir, X1);
  k_fwd_cols<<<dim3(BCN*32), 256, 0, stream>>>(X1, T2h);

  int nch = BCN/bcc;
  for(int c=0;c<nch;++c){
    int bc0 = c*bcc;
    k_b1<<<dim3(NF,16,bcc), 256, 0, stream>>>(T2h, psiP, Zh, bc0);
    k_b2<<<dim3(HW,bcc), 256, 0, stream>>>(Zh, out, part, bc0);
  }
  k_fin<<<4, 256, 0, stream>>>(part, out);
}